// Round 1
// baseline (256.976 us; speedup 1.0000x reference)
//
#include <hip/hip_runtime.h>
#include <math.h>

#define HH 2048
#define WW 2048
#define TILE 32
#define HALO 34      // TILE + 2
#define LSTRIDE 36   // pad to avoid bank-conflict on power-of-2 stride

// acc[0] = sum |fx/Econv|, acc[1] = sum |fy/Econv|, acc[2] = sum pred_E
__global__ __launch_bounds__(256) void fused_loss_kernel(
    const float* __restrict__ pred_E,
    const float* __restrict__ pred_v,
    const float* __restrict__ strain,
    float* __restrict__ acc)
{
    __shared__ float sE [HALO][LSTRIDE];
    __shared__ float sxx[HALO][LSTRIDE];
    __shared__ float syy[HALO][LSTRIDE];
    __shared__ float sxy[HALO][LSTRIDE];

    const int bi = blockIdx.y, bj = blockIdx.x;
    const int r0 = bi * TILE, c0 = bj * TILE;
    const int tid = threadIdx.x;

    // ---- stage halo tile: compute stress fields on the fly ----
    float sumE = 0.f;
    for (int idx = tid; idx < HALO * HALO; idx += 256) {
        const int li = idx / HALO;
        const int lj = idx - li * HALO;
        const int gi = r0 + li, gj = c0 + lj;
        float E = 0.f, xx = 0.f, yy = 0.f, xy = 0.f;
        if (gi < HH && gj < WW) {
            const int g = gi * WW + gj;
            E = pred_E[g];
            const float v  = pred_v[g];
            const float e0 = strain[3 * g + 0];
            const float e1 = strain[3 * g + 1];
            const float e2 = strain[3 * g + 2];
            const float frac = E / (1.f - v * v);
            xx = (e0 + v * e1) * frac;
            yy = (v * e0 + e1) * frac;
            xy = (e2 * (1.f - v) * 0.5f) * frac;
            // exclusive 32x32 interior region -> each input pixel counted once
            if (li < TILE && lj < TILE) sumE += E;
        }
        sE [li][lj] = E;
        sxx[li][lj] = xx;
        syy[li][lj] = yy;
        sxy[li][lj] = xy;
    }
    __syncthreads();

    // ---- stencils: each thread does 4 output rows ----
    float ax = 0.f, ay = 0.f;
    const int tx = tid & 31;   // column in tile
    const int ty = tid >> 5;   // 0..7
    #pragma unroll
    for (int k = 0; k < 4; ++k) {
        const int li = ty + k * 8;
        const int lj = tx;
        const int gi = r0 + li, gj = c0 + lj;
        if (gi < HH - 2 && gj < WW - 2) {
            const float Ec =
                sE[li  ][lj] + sE[li  ][lj+1] + sE[li  ][lj+2] +
                sE[li+1][lj] + sE[li+1][lj+1] + sE[li+1][lj+2] +
                sE[li+2][lj] + sE[li+2][lj+1] + sE[li+2][lj+2];
            // fx = (row li+2 - row li) of sxx + (col lj - col lj+2) of sxy
            const float fx =
                (sxx[li+2][lj] + sxx[li+2][lj+1] + sxx[li+2][lj+2]) -
                (sxx[li  ][lj] + sxx[li  ][lj+1] + sxx[li  ][lj+2]) +
                (sxy[li][lj] + sxy[li+1][lj] + sxy[li+2][lj]) -
                (sxy[li][lj+2] + sxy[li+1][lj+2] + sxy[li+2][lj+2]);
            // fy = (col lj - col lj+2) of syy + (row li+2 - row li) of sxy
            const float fy =
                (syy[li][lj] + syy[li+1][lj] + syy[li+2][lj]) -
                (syy[li][lj+2] + syy[li+1][lj+2] + syy[li+2][lj+2]) +
                (sxy[li+2][lj] + sxy[li+2][lj+1] + sxy[li+2][lj+2]) -
                (sxy[li  ][lj] + sxy[li  ][lj+1] + sxy[li  ][lj+2]);
            ax += fabsf(fx / Ec);
            ay += fabsf(fy / Ec);
        }
    }

    // ---- block reduction: wave shuffle then LDS across 4 waves ----
    #pragma unroll
    for (int off = 32; off > 0; off >>= 1) {
        ax   += __shfl_down(ax, off);
        ay   += __shfl_down(ay, off);
        sumE += __shfl_down(sumE, off);
    }
    __shared__ float red[3][4];
    const int wave = tid >> 6;
    const int lane = tid & 63;
    if (lane == 0) { red[0][wave] = ax; red[1][wave] = ay; red[2][wave] = sumE; }
    __syncthreads();
    if (tid == 0) {
        const float rx = red[0][0] + red[0][1] + red[0][2] + red[0][3];
        const float ry = red[1][0] + red[1][1] + red[1][2] + red[1][3];
        const float re = red[2][0] + red[2][1] + red[2][2] + red[2][3];
        atomicAdd(&acc[0], rx);
        atomicAdd(&acc[1], ry);
        atomicAdd(&acc[2], re);
    }
}

__global__ void finalize_kernel(const float* __restrict__ acc,
                                float* __restrict__ out)
{
    const float M = (float)((HH - 2) * (WW - 2));   // 2046*2046
    const float loss_x = acc[0] / M;
    const float loss_y = acc[1] / M;
    const float loss_e = fabsf(acc[2] / (float)(HH * WW) - 1.0f);
    out[0] = loss_x + loss_y + loss_e * 0.01f;
}

extern "C" void kernel_launch(void* const* d_in, const int* in_sizes, int n_in,
                              void* d_out, int out_size, void* d_ws, size_t ws_size,
                              hipStream_t stream) {
    const float* pred_E = (const float*)d_in[0];
    const float* pred_v = (const float*)d_in[1];
    const float* strain = (const float*)d_in[2];
    float* out = (float*)d_out;
    float* acc = (float*)d_ws;

    hipMemsetAsync(acc, 0, 3 * sizeof(float), stream);

    dim3 grid(WW / TILE, HH / TILE);   // 64 x 64 blocks cover 2046x2046 outputs
    fused_loss_kernel<<<grid, 256, 0, stream>>>(pred_E, pred_v, strain, acc);
    finalize_kernel<<<1, 1, 0, stream>>>(acc, out);
}

// Round 2
// 115.008 us; speedup vs baseline: 2.2344x; 2.2344x over previous
//
#include <hip/hip_runtime.h>
#include <math.h>

#define HH 2048
#define WW 2048
#define TILE 32
#define ROWS 34       // TILE + 2 halo rows
#define QC   9        // quad-columns staged (36 cols; cols 0..33 used by stencil)
#define LSTRIDE 36    // floats per LDS row (36*4 B = 144 B, 16B-aligned quads)
#define NBLK (64 * 64)

// Partials in d_ws: [0..4095]=sum|fx/Ec|, [4096..8191]=sum|fy/Ec|, [8192..12287]=sumE
__global__ __launch_bounds__(256) void fused_loss_kernel(
    const float* __restrict__ pred_E,
    const float* __restrict__ pred_v,
    const float* __restrict__ strain,
    float* __restrict__ part)
{
    __shared__ float sE [ROWS][LSTRIDE];
    __shared__ float sxx[ROWS][LSTRIDE];
    __shared__ float syy[ROWS][LSTRIDE];
    __shared__ float sxy[ROWS][LSTRIDE];

    const int tid = threadIdx.x;
    const int r0 = blockIdx.y * TILE, c0 = blockIdx.x * TILE;

    // ---- stage: 34 rows x 9 quad-cols = 306 quads, 2 unrolled iterations ----
    float4 E4[2], V4[2], SA[2], SB[2], SC[2];
    int rr[2], qq[2];
    bool ld[2];
    #pragma unroll
    for (int it = 0; it < 2; ++it) {
        const int idx = tid + it * 256;
        const int r = idx / QC;
        const int q = idx - r * QC;
        rr[it] = r; qq[it] = q;
        const int gi = r0 + r;
        const int gc = c0 + q * 4;
        const bool a = (idx < ROWS * QC) && (gi < HH) && (gc < WW);
        ld[it] = a;
        if (a) {
            const long g = (long)gi * WW + gc;
            E4[it] = *(const float4*)(pred_E + g);
            V4[it] = *(const float4*)(pred_v + g);
            const float* sp = strain + 3 * g;
            SA[it] = *(const float4*)(sp);
            SB[it] = *(const float4*)(sp + 4);
            SC[it] = *(const float4*)(sp + 8);
        }
    }

    float sumE = 0.f;
    #pragma unroll
    for (int it = 0; it < 2; ++it) {
        if (ld[it]) {
            const int r = rr[it], q = qq[it];
            const float e[4]  = {E4[it].x, E4[it].y, E4[it].z, E4[it].w};
            const float vv[4] = {V4[it].x, V4[it].y, V4[it].z, V4[it].w};
            const float s0[4] = {SA[it].x, SA[it].w, SB[it].z, SC[it].y};
            const float s1[4] = {SA[it].y, SB[it].x, SB[it].w, SC[it].z};
            const float s2[4] = {SA[it].z, SB[it].y, SC[it].x, SC[it].w};
            float xx[4], yy[4], xy[4];
            #pragma unroll
            for (int p = 0; p < 4; ++p) {
                const float v  = vv[p];
                const float fr = e[p] / (1.f - v * v);
                xx[p] = (s0[p] + v * s1[p]) * fr;
                yy[p] = (v * s0[p] + s1[p]) * fr;
                xy[p] = (s2[p] * (1.f - v) * 0.5f) * fr;
            }
            const int cq = 4 * q;
            *(float4*)&sE [r][cq] = E4[it];
            *(float4*)&sxx[r][cq] = make_float4(xx[0], xx[1], xx[2], xx[3]);
            *(float4*)&syy[r][cq] = make_float4(yy[0], yy[1], yy[2], yy[3]);
            *(float4*)&sxy[r][cq] = make_float4(xy[0], xy[1], xy[2], xy[3]);
            if (r < TILE && q < 8)   // exclusive 32x32 interior: each pixel once
                sumE += e[0] + e[1] + e[2] + e[3];
        }
    }
    __syncthreads();

    // ---- stencil: thread -> column tx, 4 consecutive rows, sliding sums ----
    const int tx = tid & 31;
    const int ty = tid >> 5;
    const int lb = ty * 4;

    float rsE[6], rsxx[6], rsxy[6], xyL[6], xyR[6], yyL[6], yyR[6];
    #pragma unroll
    for (int i = 0; i < 6; ++i) {
        const int r = lb + i;
        rsE[i]  = sE [r][tx] + sE [r][tx + 1] + sE [r][tx + 2];
        rsxx[i] = sxx[r][tx] + sxx[r][tx + 1] + sxx[r][tx + 2];
        const float l = sxy[r][tx], m = sxy[r][tx + 1], rg = sxy[r][tx + 2];
        xyL[i] = l; xyR[i] = rg; rsxy[i] = l + m + rg;
        yyL[i] = syy[r][tx]; yyR[i] = syy[r][tx + 2];
    }

    float ax = 0.f, ay = 0.f;
    const bool cok = (c0 + tx) < (WW - 2);
    #pragma unroll
    for (int k = 0; k < 4; ++k) {
        const int gi = r0 + lb + k;
        if (cok && gi < (HH - 2)) {
            const float Ec = rsE[k] + rsE[k + 1] + rsE[k + 2];
            const float fx = (rsxx[k + 2] - rsxx[k])
                           + (xyL[k] + xyL[k + 1] + xyL[k + 2])
                           - (xyR[k] + xyR[k + 1] + xyR[k + 2]);
            const float fy = (yyL[k] + yyL[k + 1] + yyL[k + 2])
                           - (yyR[k] + yyR[k + 1] + yyR[k + 2])
                           + (rsxy[k + 2] - rsxy[k]);
            ax += fabsf(fx / Ec);
            ay += fabsf(fy / Ec);
        }
    }

    // ---- block reduction -> per-block partials (no atomics, no memset) ----
    #pragma unroll
    for (int off = 32; off > 0; off >>= 1) {
        ax   += __shfl_down(ax, off);
        ay   += __shfl_down(ay, off);
        sumE += __shfl_down(sumE, off);
    }
    __shared__ float red[3][4];
    const int wave = tid >> 6, lane = tid & 63;
    if (lane == 0) { red[0][wave] = ax; red[1][wave] = ay; red[2][wave] = sumE; }
    __syncthreads();
    if (tid == 0) {
        const int b = blockIdx.y * 64 + blockIdx.x;
        part[b]            = red[0][0] + red[0][1] + red[0][2] + red[0][3];
        part[NBLK + b]     = red[1][0] + red[1][1] + red[1][2] + red[1][3];
        part[2 * NBLK + b] = red[2][0] + red[2][1] + red[2][2] + red[2][3];
    }
}

__global__ __launch_bounds__(256) void finalize_kernel(
    const float* __restrict__ part, float* __restrict__ out)
{
    const int tid = threadIdx.x;
    float x = 0.f, y = 0.f, e = 0.f;
    for (int i = tid; i < NBLK; i += 256) {
        x += part[i];
        y += part[NBLK + i];
        e += part[2 * NBLK + i];
    }
    #pragma unroll
    for (int off = 32; off > 0; off >>= 1) {
        x += __shfl_down(x, off);
        y += __shfl_down(y, off);
        e += __shfl_down(e, off);
    }
    __shared__ float red[3][4];
    const int wave = tid >> 6, lane = tid & 63;
    if (lane == 0) { red[0][wave] = x; red[1][wave] = y; red[2][wave] = e; }
    __syncthreads();
    if (tid == 0) {
        const float rx = red[0][0] + red[0][1] + red[0][2] + red[0][3];
        const float ry = red[1][0] + red[1][1] + red[1][2] + red[1][3];
        const float re = red[2][0] + red[2][1] + red[2][2] + red[2][3];
        const float M = (float)((HH - 2) * (WW - 2));
        const float loss_x = rx / M;
        const float loss_y = ry / M;
        const float loss_e = fabsf(re / (float)(HH * WW) - 1.0f);
        out[0] = loss_x + loss_y + loss_e * 0.01f;
    }
}

extern "C" void kernel_launch(void* const* d_in, const int* in_sizes, int n_in,
                              void* d_out, int out_size, void* d_ws, size_t ws_size,
                              hipStream_t stream) {
    const float* pred_E = (const float*)d_in[0];
    const float* pred_v = (const float*)d_in[1];
    const float* strain = (const float*)d_in[2];
    float* out  = (float*)d_out;
    float* part = (float*)d_ws;   // 3 * 4096 floats = 48 KB

    dim3 grid(WW / TILE, HH / TILE);   // 64 x 64
    fused_loss_kernel<<<grid, 256, 0, stream>>>(pred_E, pred_v, strain, part);
    finalize_kernel<<<1, 256, 0, stream>>>(part, out);
}

// Round 3
// 110.372 us; speedup vs baseline: 2.3283x; 1.0420x over previous
//
#include <hip/hip_runtime.h>
#include <math.h>

#define HH 2048
#define WW 2048
#define TILE 32
#define ROWS 34       // TILE + 2 halo rows
#define QC   9        // quad-columns staged (36 cols; cols 0..33 used)
#define LSTRIDE 36    // floats per LDS row (144 B, 16B-aligned quads)
#define NBLK (64 * 64)

// v_rcp_f32: ~1 ulp relative error — absmax threshold is 0.28, so free.
__device__ __forceinline__ float rcpf(float x) { return __builtin_amdgcn_rcpf(x); }

// Partials in d_ws: [0..4095]=sum|fx/Ec|, [4096..8191]=sum|fy/Ec|, [8192..12287]=sumE
__global__ __launch_bounds__(256) void fused_loss_kernel(
    const float* __restrict__ pred_E,
    const float* __restrict__ pred_v,
    const float* __restrict__ strain,
    float* __restrict__ part)
{
    __shared__ float sE [ROWS][LSTRIDE];
    __shared__ float sxx[ROWS][LSTRIDE];
    __shared__ float syy[ROWS][LSTRIDE];
    __shared__ float sxy[ROWS][LSTRIDE];

    const int tid = threadIdx.x;
    const int r0 = blockIdx.y * TILE, c0 = blockIdx.x * TILE;

    // ---- stage: 34 rows x 9 quad-cols = 306 quads, all loads issued first ----
    float4 E4[2], V4[2], SA[2], SB[2], SC[2];
    int rr[2], qq[2];
    bool ld[2];
    #pragma unroll
    for (int it = 0; it < 2; ++it) {
        const int idx = tid + it * 256;
        const int r = idx / QC;
        const int q = idx - r * QC;
        rr[it] = r; qq[it] = q;
        const int gi = r0 + r;
        const int gc = c0 + q * 4;
        const bool a = (idx < ROWS * QC) && (gi < HH) && (gc < WW);
        ld[it] = a;
        if (a) {
            const int g = gi * WW + gc;
            E4[it] = *(const float4*)(pred_E + g);
            V4[it] = *(const float4*)(pred_v + g);
            const float* sp = strain + 3 * g;
            SA[it] = *(const float4*)(sp);
            SB[it] = *(const float4*)(sp + 4);
            SC[it] = *(const float4*)(sp + 8);
        }
    }

    float sumE = 0.f;
    #pragma unroll
    for (int it = 0; it < 2; ++it) {
        if (ld[it]) {
            const int r = rr[it], q = qq[it];
            const float e[4]  = {E4[it].x, E4[it].y, E4[it].z, E4[it].w};
            const float vv[4] = {V4[it].x, V4[it].y, V4[it].z, V4[it].w};
            const float s0[4] = {SA[it].x, SA[it].w, SB[it].z, SC[it].y};
            const float s1[4] = {SA[it].y, SB[it].x, SB[it].w, SC[it].z};
            const float s2[4] = {SA[it].z, SB[it].y, SC[it].x, SC[it].w};
            float xx[4], yy[4], xy[4];
            #pragma unroll
            for (int p = 0; p < 4; ++p) {
                const float v  = vv[p];
                const float fr = e[p] * rcpf(1.f - v * v);
                xx[p] = (s0[p] + v * s1[p]) * fr;
                yy[p] = (v * s0[p] + s1[p]) * fr;
                xy[p] = (s2[p] * (1.f - v) * 0.5f) * fr;
            }
            const int cq = 4 * q;
            *(float4*)&sE [r][cq] = E4[it];
            *(float4*)&sxx[r][cq] = make_float4(xx[0], xx[1], xx[2], xx[3]);
            *(float4*)&syy[r][cq] = make_float4(yy[0], yy[1], yy[2], yy[3]);
            *(float4*)&sxy[r][cq] = make_float4(xy[0], xy[1], xy[2], xy[3]);
            if (r < TILE && q < 8)   // exclusive 32x32 interior: each pixel once
                sumE += e[0] + e[1] + e[2] + e[3];
        }
    }
    __syncthreads();

    // ---- stencil: thread -> column tx, 4 consecutive rows, sliding sums ----
    const int tx = tid & 31;
    const int ty = tid >> 5;
    const int lb = ty * 4;

    float rsE[6], rsxx[6], rsxy[6], xyL[6], xyR[6], yyL[6], yyR[6];
    #pragma unroll
    for (int i = 0; i < 6; ++i) {
        const int r = lb + i;
        rsE[i]  = sE [r][tx] + sE [r][tx + 1] + sE [r][tx + 2];
        rsxx[i] = sxx[r][tx] + sxx[r][tx + 1] + sxx[r][tx + 2];
        const float l = sxy[r][tx], m = sxy[r][tx + 1], rg = sxy[r][tx + 2];
        xyL[i] = l; xyR[i] = rg; rsxy[i] = l + m + rg;
        yyL[i] = syy[r][tx]; yyR[i] = syy[r][tx + 2];
    }

    float ax = 0.f, ay = 0.f;
    const bool cok = (c0 + tx) < (WW - 2);
    #pragma unroll
    for (int k = 0; k < 4; ++k) {
        const int gi = r0 + lb + k;
        if (cok && gi < (HH - 2)) {
            // Ec > 0 always (E ~ U(0,1) sums) -> one rcp serves both terms
            const float rEc = rcpf(rsE[k] + rsE[k + 1] + rsE[k + 2]);
            const float fx = (rsxx[k + 2] - rsxx[k])
                           + (xyL[k] + xyL[k + 1] + xyL[k + 2])
                           - (xyR[k] + xyR[k + 1] + xyR[k + 2]);
            const float fy = (yyL[k] + yyL[k + 1] + yyL[k + 2])
                           - (yyR[k] + yyR[k + 1] + yyR[k + 2])
                           + (rsxy[k + 2] - rsxy[k]);
            ax += fabsf(fx) * rEc;
            ay += fabsf(fy) * rEc;
        }
    }

    // ---- block reduction -> per-block partials (no atomics, no memset) ----
    #pragma unroll
    for (int off = 32; off > 0; off >>= 1) {
        ax   += __shfl_down(ax, off);
        ay   += __shfl_down(ay, off);
        sumE += __shfl_down(sumE, off);
    }
    __shared__ float red[3][4];
    const int wave = tid >> 6, lane = tid & 63;
    if (lane == 0) { red[0][wave] = ax; red[1][wave] = ay; red[2][wave] = sumE; }
    __syncthreads();
    if (tid == 0) {
        const int b = blockIdx.y * 64 + blockIdx.x;
        part[b]            = red[0][0] + red[0][1] + red[0][2] + red[0][3];
        part[NBLK + b]     = red[1][0] + red[1][1] + red[1][2] + red[1][3];
        part[2 * NBLK + b] = red[2][0] + red[2][1] + red[2][2] + red[2][3];
    }
}

__global__ __launch_bounds__(256) void finalize_kernel(
    const float* __restrict__ part, float* __restrict__ out)
{
    const int tid = threadIdx.x;
    const float4* px = (const float4*)(part);
    const float4* py = (const float4*)(part + NBLK);
    const float4* pe = (const float4*)(part + 2 * NBLK);
    float x = 0.f, y = 0.f, e = 0.f;
    #pragma unroll
    for (int k = 0; k < 4; ++k) {          // 1024 float4 per plane / 256 threads
        const int i = tid + k * 256;
        const float4 a = px[i], b = py[i], c = pe[i];
        x += a.x + a.y + a.z + a.w;
        y += b.x + b.y + b.z + b.w;
        e += c.x + c.y + c.z + c.w;
    }
    #pragma unroll
    for (int off = 32; off > 0; off >>= 1) {
        x += __shfl_down(x, off);
        y += __shfl_down(y, off);
        e += __shfl_down(e, off);
    }
    __shared__ float red[3][4];
    const int wave = tid >> 6, lane = tid & 63;
    if (lane == 0) { red[0][wave] = x; red[1][wave] = y; red[2][wave] = e; }
    __syncthreads();
    if (tid == 0) {
        const float rx = red[0][0] + red[0][1] + red[0][2] + red[0][3];
        const float ry = red[1][0] + red[1][1] + red[1][2] + red[1][3];
        const float re = red[2][0] + red[2][1] + red[2][2] + red[2][3];
        const float M = (float)((HH - 2) * (WW - 2));
        const float loss_x = rx / M;
        const float loss_y = ry / M;
        const float loss_e = fabsf(re / (float)(HH * WW) - 1.0f);
        out[0] = loss_x + loss_y + loss_e * 0.01f;
    }
}

extern "C" void kernel_launch(void* const* d_in, const int* in_sizes, int n_in,
                              void* d_out, int out_size, void* d_ws, size_t ws_size,
                              hipStream_t stream) {
    const float* pred_E = (const float*)d_in[0];
    const float* pred_v = (const float*)d_in[1];
    const float* strain = (const float*)d_in[2];
    float* out  = (float*)d_out;
    float* part = (float*)d_ws;   // 3 * 4096 floats = 48 KB

    dim3 grid(WW / TILE, HH / TILE);   // 64 x 64
    fused_loss_kernel<<<grid, 256, 0, stream>>>(pred_E, pred_v, strain, part);
    finalize_kernel<<<1, 256, 0, stream>>>(part, out);
}

// Round 4
// 109.852 us; speedup vs baseline: 2.3393x; 1.0047x over previous
//
#include <hip/hip_runtime.h>
#include <math.h>

#define HH 2048
#define WW 2048
#define TILE 32
#define ROWS 34       // TILE + 2 halo rows
#define QC   9        // quad-columns staged per tile (36 cols; 0..33 used)
#define LSTRIDE 36    // floats per LDS row (144 B, 16B-aligned quads)
#define NBLK (32 * 64)  // 32 tile-pairs in x, 64 tile rows in y

// v_rcp_f32: ~1 ulp relative error — absmax threshold is 0.28, so free.
__device__ __forceinline__ float rcpf(float x) { return __builtin_amdgcn_rcpf(x); }

struct StageRegs {
    float4 E, V, A, B, C;
    int r, q;
    bool ld;
};

// Issue all 10 dwordx4 loads for one 34x36 tile (2 reg-sets per thread).
__device__ __forceinline__ void stage_load(
    const float* __restrict__ pred_E, const float* __restrict__ pred_v,
    const float* __restrict__ strain, int r0, int c0, int tid, StageRegs R[2])
{
    #pragma unroll
    for (int it = 0; it < 2; ++it) {
        const int idx = tid + it * 256;
        const int r = idx / QC;
        const int q = idx - r * QC;
        R[it].r = r; R[it].q = q;
        const int gi = r0 + r;
        const int gc = c0 + q * 4;
        const bool a = (idx < ROWS * QC) && (gi < HH) && (gc < WW);
        R[it].ld = a;
        if (a) {
            const int g = gi * WW + gc;
            R[it].E = *(const float4*)(pred_E + g);
            R[it].V = *(const float4*)(pred_v + g);
            const float* sp = strain + 3 * g;
            R[it].A = *(const float4*)(sp);
            R[it].B = *(const float4*)(sp + 4);
            R[it].C = *(const float4*)(sp + 8);
        }
    }
}

// Plane-stress math + LDS store; accumulates interior sum(E).
__device__ __forceinline__ void stage_math_store(
    StageRegs R[2], float& sumE,
    float (*sE)[LSTRIDE], float (*sxx)[LSTRIDE],
    float (*syy)[LSTRIDE], float (*sxy)[LSTRIDE])
{
    #pragma unroll
    for (int it = 0; it < 2; ++it) {
        if (R[it].ld) {
            const int r = R[it].r, q = R[it].q;
            const float e[4]  = {R[it].E.x, R[it].E.y, R[it].E.z, R[it].E.w};
            const float vv[4] = {R[it].V.x, R[it].V.y, R[it].V.z, R[it].V.w};
            const float s0[4] = {R[it].A.x, R[it].A.w, R[it].B.z, R[it].C.y};
            const float s1[4] = {R[it].A.y, R[it].B.x, R[it].B.w, R[it].C.z};
            const float s2[4] = {R[it].A.z, R[it].B.y, R[it].C.x, R[it].C.w};
            float xx[4], yy[4], xy[4];
            #pragma unroll
            for (int p = 0; p < 4; ++p) {
                const float v  = vv[p];
                const float fr = e[p] * rcpf(1.f - v * v);
                xx[p] = (s0[p] + v * s1[p]) * fr;
                yy[p] = (v * s0[p] + s1[p]) * fr;
                xy[p] = (s2[p] * (1.f - v) * 0.5f) * fr;
            }
            const int cq = 4 * q;
            *(float4*)&sE [r][cq] = R[it].E;
            *(float4*)&sxx[r][cq] = make_float4(xx[0], xx[1], xx[2], xx[3]);
            *(float4*)&syy[r][cq] = make_float4(yy[0], yy[1], yy[2], yy[3]);
            *(float4*)&sxy[r][cq] = make_float4(xy[0], xy[1], xy[2], xy[3]);
            if (r < TILE && q < 8)   // exclusive 32x32 interior: each pixel once
                sumE += e[0] + e[1] + e[2] + e[3];
        }
    }
}

// 3x3 stencils via sliding row sums; accumulates |fx/Ec| and |fy/Ec|.
__device__ __forceinline__ void stencil(
    int r0, int c0, int tid, float& ax, float& ay,
    float (*sE)[LSTRIDE], float (*sxx)[LSTRIDE],
    float (*syy)[LSTRIDE], float (*sxy)[LSTRIDE])
{
    const int tx = tid & 31;
    const int ty = tid >> 5;
    const int lb = ty * 4;

    float rsE[6], rsxx[6], rsxy[6], xyL[6], xyR[6], yyL[6], yyR[6];
    #pragma unroll
    for (int i = 0; i < 6; ++i) {
        const int r = lb + i;
        rsE[i]  = sE [r][tx] + sE [r][tx + 1] + sE [r][tx + 2];
        rsxx[i] = sxx[r][tx] + sxx[r][tx + 1] + sxx[r][tx + 2];
        const float l = sxy[r][tx], m = sxy[r][tx + 1], rg = sxy[r][tx + 2];
        xyL[i] = l; xyR[i] = rg; rsxy[i] = l + m + rg;
        yyL[i] = syy[r][tx]; yyR[i] = syy[r][tx + 2];
    }

    const bool cok = (c0 + tx) < (WW - 2);
    #pragma unroll
    for (int k = 0; k < 4; ++k) {
        const int gi = r0 + lb + k;
        if (cok && gi < (HH - 2)) {
            const float rEc = rcpf(rsE[k] + rsE[k + 1] + rsE[k + 2]);
            const float fx = (rsxx[k + 2] - rsxx[k])
                           + (xyL[k] + xyL[k + 1] + xyL[k + 2])
                           - (xyR[k] + xyR[k + 1] + xyR[k + 2]);
            const float fy = (yyL[k] + yyL[k + 1] + yyL[k + 2])
                           - (yyR[k] + yyR[k + 1] + yyR[k + 2])
                           + (rsxy[k + 2] - rsxy[k]);
            ax += fabsf(fx) * rEc;
            ay += fabsf(fy) * rEc;
        }
    }
}

// Partials in d_ws: [0..2047]=sum|fx/Ec|, [2048..4095]=sum|fy/Ec|, [4096..6143]=sumE
__global__ __launch_bounds__(256, 4) void fused_loss_kernel(
    const float* __restrict__ pred_E,
    const float* __restrict__ pred_v,
    const float* __restrict__ strain,
    float* __restrict__ part)
{
    __shared__ float sE [ROWS][LSTRIDE];
    __shared__ float sxx[ROWS][LSTRIDE];
    __shared__ float syy[ROWS][LSTRIDE];
    __shared__ float sxy[ROWS][LSTRIDE];

    const int tid = threadIdx.x;
    const int r0 = blockIdx.y * TILE;
    const int c0 = blockIdx.x * (2 * TILE);   // tile pair: c0 and c0+TILE

    float sumE = 0.f, ax = 0.f, ay = 0.f;
    StageRegs R0[2], R1[2];

    // ---- software pipeline across the two tiles ----
    stage_load(pred_E, pred_v, strain, r0, c0, tid, R0);          // t0 loads
    stage_math_store(R0, sumE, sE, sxx, syy, sxy);                // t0 math->LDS
    __syncthreads();
    stage_load(pred_E, pred_v, strain, r0, c0 + TILE, tid, R1);   // t1 loads (in flight)
    stencil(r0, c0, tid, ax, ay, sE, sxx, syy, sxy);              // t0 stencil overlaps t1 loads
    __syncthreads();                                              // LDS t0 reads done
    stage_math_store(R1, sumE, sE, sxx, syy, sxy);                // t1 math->LDS
    __syncthreads();
    stencil(r0, c0 + TILE, tid, ax, ay, sE, sxx, syy, sxy);       // t1 stencil

    // ---- block reduction -> per-block partials ----
    #pragma unroll
    for (int off = 32; off > 0; off >>= 1) {
        ax   += __shfl_down(ax, off);
        ay   += __shfl_down(ay, off);
        sumE += __shfl_down(sumE, off);
    }
    __shared__ float red[3][4];
    const int wave = tid >> 6, lane = tid & 63;
    if (lane == 0) { red[0][wave] = ax; red[1][wave] = ay; red[2][wave] = sumE; }
    __syncthreads();
    if (tid == 0) {
        const int b = blockIdx.y * 32 + blockIdx.x;
        part[b]            = red[0][0] + red[0][1] + red[0][2] + red[0][3];
        part[NBLK + b]     = red[1][0] + red[1][1] + red[1][2] + red[1][3];
        part[2 * NBLK + b] = red[2][0] + red[2][1] + red[2][2] + red[2][3];
    }
}

__global__ __launch_bounds__(256) void finalize_kernel(
    const float* __restrict__ part, float* __restrict__ out)
{
    const int tid = threadIdx.x;
    const float4* px = (const float4*)(part);
    const float4* py = (const float4*)(part + NBLK);
    const float4* pe = (const float4*)(part + 2 * NBLK);
    float x = 0.f, y = 0.f, e = 0.f;
    #pragma unroll
    for (int k = 0; k < 2; ++k) {          // 512 float4 per plane / 256 threads
        const int i = tid + k * 256;
        const float4 a = px[i], b = py[i], c = pe[i];
        x += a.x + a.y + a.z + a.w;
        y += b.x + b.y + b.z + b.w;
        e += c.x + c.y + c.z + c.w;
    }
    #pragma unroll
    for (int off = 32; off > 0; off >>= 1) {
        x += __shfl_down(x, off);
        y += __shfl_down(y, off);
        e += __shfl_down(e, off);
    }
    __shared__ float red[3][4];
    const int wave = tid >> 6, lane = tid & 63;
    if (lane == 0) { red[0][wave] = x; red[1][wave] = y; red[2][wave] = e; }
    __syncthreads();
    if (tid == 0) {
        const float rx = red[0][0] + red[0][1] + red[0][2] + red[0][3];
        const float ry = red[1][0] + red[1][1] + red[1][2] + red[1][3];
        const float re = red[2][0] + red[2][1] + red[2][2] + red[2][3];
        const float M = (float)((HH - 2) * (WW - 2));
        const float loss_x = rx / M;
        const float loss_y = ry / M;
        const float loss_e = fabsf(re / (float)(HH * WW) - 1.0f);
        out[0] = loss_x + loss_y + loss_e * 0.01f;
    }
}

extern "C" void kernel_launch(void* const* d_in, const int* in_sizes, int n_in,
                              void* d_out, int out_size, void* d_ws, size_t ws_size,
                              hipStream_t stream) {
    const float* pred_E = (const float*)d_in[0];
    const float* pred_v = (const float*)d_in[1];
    const float* strain = (const float*)d_in[2];
    float* out  = (float*)d_out;
    float* part = (float*)d_ws;   // 3 * 2048 floats = 24 KB

    dim3 grid(WW / (2 * TILE), HH / TILE);   // 32 x 64 = 2048 blocks
    fused_loss_kernel<<<grid, 256, 0, stream>>>(pred_E, pred_v, strain, part);
    finalize_kernel<<<1, 256, 0, stream>>>(part, out);
}